// Round 4
// baseline (2594.578 us; speedup 1.0000x reference)
//
#include <hip/hip_runtime.h>
#include <hip/hip_bf16.h>

// ---------------------------------------------------------------------------
// Types / helpers
// ---------------------------------------------------------------------------
typedef __bf16 bf16x8 __attribute__((ext_vector_type(8)));
typedef float f32x4 __attribute__((ext_vector_type(4)));

// fp32 -> bf16 bits, round-to-nearest-even (inputs are finite; no NaN path)
__device__ __forceinline__ unsigned short f2bs(float f) {
    unsigned u = __builtin_bit_cast(unsigned, f);
    u = (u + 0x7fffu + ((u >> 16) & 1u)) >> 16;
    return (unsigned short)u;
}

#define GLDS16(gp, lp)                                                        \
    __builtin_amdgcn_global_load_lds(                                         \
        (const __attribute__((address_space(1))) void*)(gp),                  \
        (__attribute__((address_space(3))) void*)(lp), 16, 0, 0)

#define TCHUNK 32

// ---------------------------------------------------------------------------
// Kernel 1a: per-chunk sums. partial[b][c][d] = sum_{t in chunk c} h[b][t][d]
// grid (B, nC, D/256), block 256.
// ---------------------------------------------------------------------------
__global__ __launch_bounds__(256) void feats_partial(
    const float* __restrict__ h, float* __restrict__ partial,
    int B, int T, int D, int nC) {
    const int d = blockIdx.z * 256 + threadIdx.x;
    const int b = blockIdx.x, c = blockIdx.y;
    const int t0 = c * TCHUNK;
    const int t1 = min(t0 + TCHUNK, T);
    const float* hp = h + ((long)b * T + t0) * D + d;
    float s = 0.f;
    for (int t = t0; t < t1; ++t) { s += *hp; hp += D; }
    partial[((long)b * nC + c) * D + d] = s;
}

// ---------------------------------------------------------------------------
// Kernel 1b: write X. X[m,0:D) = exclusive prefix mean, X[m,D:2D) = h.
// Each block handles one (b, chunk); starts from the scanned chunk prefix.
// grid (B, nC, D/256), block 256. fp32 running sum for accuracy.
// ---------------------------------------------------------------------------
__global__ __launch_bounds__(256) void feats_write(
    const float* __restrict__ h, const float* __restrict__ partial,
    unsigned short* __restrict__ X, int B, int T, int D, int nC) {
    const int d = blockIdx.z * 256 + threadIdx.x;
    const int b = blockIdx.x, c = blockIdx.y;
    const int t0 = c * TCHUNK;
    const int t1 = min(t0 + TCHUNK, T);
    float sum = 0.f;
    for (int cc = 0; cc < c; ++cc)
        sum += partial[((long)b * nC + cc) * D + d];
    const float* hp = h + ((long)b * T + t0) * D + d;
    unsigned short* xp = X + ((long)b * T + t0) * (2 * D) + d;
    for (int t = t0; t < t1; ++t) {
        float pm = (t == 0) ? 0.f : sum / (float)t;
        float v = *hp;
        xp[0] = f2bs(pm);
        xp[D] = f2bs(v);
        sum += v;
        hp += D;
        xp += 2 * D;
    }
}

// ---------------------------------------------------------------------------
// Kernel 2: transpose + cast. W: [K][N] fp32 -> WT: [N][K] bf16 bits.
// grid (N/32, K/32), block (32, 8)
// ---------------------------------------------------------------------------
__global__ __launch_bounds__(256) void transpose_cast(
    const float* __restrict__ W, unsigned short* __restrict__ WT,
    int K, int N) {
    __shared__ float tile[32][33];
    const int n0 = blockIdx.x * 32, k0 = blockIdx.y * 32;
    const int tx = threadIdx.x, ty = threadIdx.y;
    #pragma unroll
    for (int i = ty; i < 32; i += 8)
        tile[i][tx] = W[(long)(k0 + i) * N + n0 + tx];
    __syncthreads();
    #pragma unroll
    for (int i = ty; i < 32; i += 8)
        WT[(long)(n0 + i) * K + k0 + tx] = f2bs(tile[tx][i]);
}

// ---------------------------------------------------------------------------
// Kernel 2b: out[m] = b3 (init for the fused-head atomics)
// ---------------------------------------------------------------------------
__global__ __launch_bounds__(256) void init_out(
    float* __restrict__ out, const float* __restrict__ b3, int M) {
    int m = blockIdx.x * 256 + threadIdx.x;
    if (m < M) out[m] = b3[0];
}

// ---------------------------------------------------------------------------
// Kernel 3: GEMM  C[M,N] = relu(A[M,K] * BT[N,K]^T + bias)
// m97 structure: 128x128 tile, BK=32, 4 waves 2x2, 16x16x32 bf16 MFMA,
// global_load_lds width 16. grid (N/128, M/128): fast dim walks the column
// blocks of one A row-panel (cache reuse).
// NOTE (R3 lesson): do NOT bank-swizzle here — conflicts are fully hidden by
// wave overlap; the swizzle's +4 VGPR cost a wave/EU (84->88 crosses 512/6)
// and regressed 308->342 us. __launch_bounds__(256,6) pins 6 waves/EU.
// FUSE: head layer folded into the epilogue via lane16 shuffle-reduce +
// one atomicAdd per row-slot.
// ---------------------------------------------------------------------------
template <bool FUSE>
__global__ __launch_bounds__(256, 6) void gemm_bt_bias_relu(
    const unsigned short* __restrict__ A,   // [M,K] bf16 bits
    const unsigned short* __restrict__ BT,  // [N,K] bf16 bits
    const float* __restrict__ bias,         // [N]
    unsigned short* __restrict__ C,         // [M,N] bf16 bits (unused if FUSE)
    const float* __restrict__ W3,           // [N] head weights (FUSE only)
    float* __restrict__ outp,               // [M] (FUSE only)
    int M, int N, int K) {
    __shared__ __align__(16) unsigned short As[128 * 32];
    __shared__ __align__(16) unsigned short Bs[128 * 32];

    const int tid = threadIdx.x;
    const int lane = tid & 63;
    const int wave = tid >> 6;
    const int wm = (wave >> 1) * 64;
    const int wn = (wave & 1) * 64;
    const int lane16 = lane & 15;
    const int quad = lane >> 4;

    const long row0 = (long)blockIdx.y * 128;
    const long col0 = (long)blockIdx.x * 128;

    const unsigned short* Ab = A + row0 * K;
    const unsigned short* Bb = BT + col0 * K;

    const int sr = tid >> 2;         // staging row 0..63
    const int sc = (tid & 3) * 8;    // staging col (elements)

    f32x4 acc[4][4];
    #pragma unroll
    for (int i = 0; i < 4; ++i)
        #pragma unroll
        for (int j = 0; j < 4; ++j)
            acc[i][j] = (f32x4){0.f, 0.f, 0.f, 0.f};

    for (int kt = 0; kt < K; kt += 32) {
        GLDS16(Ab + (long)sr * K + kt + sc,        As + tid * 8);
        GLDS16(Ab + (long)(sr + 64) * K + kt + sc, As + (256 + tid) * 8);
        GLDS16(Bb + (long)sr * K + kt + sc,        Bs + tid * 8);
        GLDS16(Bb + (long)(sr + 64) * K + kt + sc, Bs + (256 + tid) * 8);
        __syncthreads();

        bf16x8 af[4], bfr[4];
        #pragma unroll
        for (int i = 0; i < 4; ++i)
            af[i] = *(const bf16x8*)(As + (wm + i * 16 + lane16) * 32 + quad * 8);
        #pragma unroll
        for (int j = 0; j < 4; ++j)
            bfr[j] = *(const bf16x8*)(Bs + (wn + j * 16 + lane16) * 32 + quad * 8);

        #pragma unroll
        for (int i = 0; i < 4; ++i)
            #pragma unroll
            for (int j = 0; j < 4; ++j)
                acc[i][j] = __builtin_amdgcn_mfma_f32_16x16x32_bf16(
                    af[i], bfr[j], acc[i][j], 0, 0, 0);

        __syncthreads();
    }

    // Epilogue: C/D layout col=lane&15, row=quad*4+reg  (m89/m91 verified)
    if (!FUSE) {
        #pragma unroll
        for (int i = 0; i < 4; ++i) {
            #pragma unroll
            for (int r = 0; r < 4; ++r) {
                const long row = row0 + wm + i * 16 + quad * 4 + r;
                #pragma unroll
                for (int j = 0; j < 4; ++j) {
                    const long col = col0 + wn + j * 16 + lane16;
                    float v = acc[i][j][r] + bias[col];
                    v = fmaxf(v, 0.f);
                    C[row * N + col] = f2bs(v);
                }
            }
        }
    } else {
        // head fusion: sum over this lane's 4 cols of relu(v)*W3
        float w3v[4], bv[4];
        #pragma unroll
        for (int j = 0; j < 4; ++j) {
            const long col = col0 + wn + j * 16 + lane16;
            w3v[j] = W3[col];
            bv[j] = bias[col];
        }
        #pragma unroll
        for (int i = 0; i < 4; ++i) {
            #pragma unroll
            for (int r = 0; r < 4; ++r) {
                float s = 0.f;
                #pragma unroll
                for (int j = 0; j < 4; ++j) {
                    float v = fmaxf(acc[i][j][r] + bv[j], 0.f);
                    s += v * w3v[j];
                }
                s += __shfl_xor(s, 1, 64);
                s += __shfl_xor(s, 2, 64);
                s += __shfl_xor(s, 4, 64);
                s += __shfl_xor(s, 8, 64);
                if (lane16 == 0) {
                    const long row = row0 + wm + i * 16 + quad * 4 + r;
                    atomicAdd(&outp[row], s);
                }
            }
        }
    }
}

// ---------------------------------------------------------------------------
// Launch
// ---------------------------------------------------------------------------
extern "C" void kernel_launch(void* const* d_in, const int* in_sizes, int n_in,
                              void* d_out, int out_size, void* d_ws,
                              size_t ws_size, hipStream_t stream) {
    const float* h  = (const float*)d_in[0];
    const float* W1 = (const float*)d_in[1];
    const float* b1 = (const float*)d_in[2];
    const float* W2 = (const float*)d_in[3];
    const float* b2 = (const float*)d_in[4];
    const float* W3 = (const float*)d_in[5];
    const float* b3 = (const float*)d_in[6];
    float* out = (float*)d_out;

    const int B = 128, T = 254, D = 768, H = 1024;
    const int M = B * T;        // 32512
    const int K1 = 2 * D;       // 1536
    const int N1 = 2 * H;       // 2048
    const int K2 = N1;          // 2048
    const int N2 = H;           // 1024
    const int nC = (T + TCHUNK - 1) / TCHUNK;  // 8

    char* ws = (char*)d_ws;
    size_t off = 0;
    auto alloc = [&](size_t bytes) {
        char* p = ws + off;
        off += (bytes + 255) & ~(size_t)255;
        return p;
    };
    unsigned short* X   = (unsigned short*)alloc((size_t)M * K1 * 2);  // 99.9 MB
    unsigned short* H1  = (unsigned short*)alloc((size_t)M * N1 * 2);  // 133.2 MB
    unsigned short* W1T = (unsigned short*)alloc((size_t)N1 * K1 * 2); // 6.3 MB
    unsigned short* W2T = (unsigned short*)alloc((size_t)N2 * K2 * 2); // 4.2 MB
    float* partial      = (float*)alloc((size_t)B * nC * D * 4);       // 3.1 MB

    dim3 tb(32, 8);
    transpose_cast<<<dim3(N1 / 32, K1 / 32), tb, 0, stream>>>(W1, W1T, K1, N1);
    transpose_cast<<<dim3(N2 / 32, K2 / 32), tb, 0, stream>>>(W2, W2T, K2, N2);

    feats_partial<<<dim3(B, nC, D / 256), 256, 0, stream>>>(
        h, partial, B, T, D, nC);
    feats_write<<<dim3(B, nC, D / 256), 256, 0, stream>>>(
        h, partial, X, B, T, D, nC);

    init_out<<<dim3((M + 255) / 256), 256, 0, stream>>>(out, b3, M);

    // grid (Ncols, Mrows): fast dim = column blocks -> A panel reuse in cache
    gemm_bt_bias_relu<false><<<dim3(N1 / 128, M / 128), 256, 0, stream>>>(
        X, W1T, b1, H1, nullptr, nullptr, M, N1, K1);
    gemm_bt_bias_relu<true><<<dim3(N2 / 128, M / 128), 256, 0, stream>>>(
        H1, W2T, b2, nullptr, W3, out, M, N2, K2);
}

// Round 5
// 676.737 us; speedup vs baseline: 3.8340x; 3.8340x over previous
//
#include <hip/hip_runtime.h>
#include <hip/hip_bf16.h>

// ---------------------------------------------------------------------------
// Types / helpers
// ---------------------------------------------------------------------------
typedef __bf16 bf16x8 __attribute__((ext_vector_type(8)));
typedef float f32x4 __attribute__((ext_vector_type(4)));

// fp32 -> bf16 bits, round-to-nearest-even (inputs are finite; no NaN path)
__device__ __forceinline__ unsigned short f2bs(float f) {
    unsigned u = __builtin_bit_cast(unsigned, f);
    u = (u + 0x7fffu + ((u >> 16) & 1u)) >> 16;
    return (unsigned short)u;
}

#define GLDS16(gp, lp)                                                        \
    __builtin_amdgcn_global_load_lds(                                         \
        (const __attribute__((address_space(1))) void*)(gp),                  \
        (__attribute__((address_space(3))) void*)(lp), 16, 0, 0)

#define TCHUNK 32

// ---------------------------------------------------------------------------
// Kernel 1a: per-chunk sums. partial[b][c][d] = sum_{t in chunk c} h[b][t][d]
// grid (B, nC, D/256), block 256.
// ---------------------------------------------------------------------------
__global__ __launch_bounds__(256) void feats_partial(
    const float* __restrict__ h, float* __restrict__ partial,
    int B, int T, int D, int nC) {
    const int d = blockIdx.z * 256 + threadIdx.x;
    const int b = blockIdx.x, c = blockIdx.y;
    const int t0 = c * TCHUNK;
    const int t1 = min(t0 + TCHUNK, T);
    const float* hp = h + ((long)b * T + t0) * D + d;
    float s = 0.f;
    for (int t = t0; t < t1; ++t) { s += *hp; hp += D; }
    partial[((long)b * nC + c) * D + d] = s;
}

// ---------------------------------------------------------------------------
// Kernel 1b: write X. X[m,0:D) = exclusive prefix mean, X[m,D:2D) = h.
// Each block handles one (b, chunk); starts from the scanned chunk prefix.
// grid (B, nC, D/256), block 256. fp32 running sum for accuracy.
// ---------------------------------------------------------------------------
__global__ __launch_bounds__(256) void feats_write(
    const float* __restrict__ h, const float* __restrict__ partial,
    unsigned short* __restrict__ X, int B, int T, int D, int nC) {
    const int d = blockIdx.z * 256 + threadIdx.x;
    const int b = blockIdx.x, c = blockIdx.y;
    const int t0 = c * TCHUNK;
    const int t1 = min(t0 + TCHUNK, T);
    float sum = 0.f;
    for (int cc = 0; cc < c; ++cc)
        sum += partial[((long)b * nC + cc) * D + d];
    const float* hp = h + ((long)b * T + t0) * D + d;
    unsigned short* xp = X + ((long)b * T + t0) * (2 * D) + d;
    for (int t = t0; t < t1; ++t) {
        float pm = (t == 0) ? 0.f : sum / (float)t;
        float v = *hp;
        xp[0] = f2bs(pm);
        xp[D] = f2bs(v);
        sum += v;
        hp += D;
        xp += 2 * D;
    }
}

// ---------------------------------------------------------------------------
// Kernel 2: transpose + cast. W: [K][N] fp32 -> WT: [N][K] bf16 bits.
// grid (N/32, K/32), block (32, 8)
// ---------------------------------------------------------------------------
__global__ __launch_bounds__(256) void transpose_cast(
    const float* __restrict__ W, unsigned short* __restrict__ WT,
    int K, int N) {
    __shared__ float tile[32][33];
    const int n0 = blockIdx.x * 32, k0 = blockIdx.y * 32;
    const int tx = threadIdx.x, ty = threadIdx.y;
    #pragma unroll
    for (int i = ty; i < 32; i += 8)
        tile[i][tx] = W[(long)(k0 + i) * N + n0 + tx];
    __syncthreads();
    #pragma unroll
    for (int i = ty; i < 32; i += 8)
        WT[(long)(n0 + i) * K + k0 + tx] = f2bs(tile[tx][i]);
}

// ---------------------------------------------------------------------------
// Kernel 2b: out[m] = b3 (init for the fused-head atomics)
// ---------------------------------------------------------------------------
__global__ __launch_bounds__(256) void init_out(
    float* __restrict__ out, const float* __restrict__ b3, int M) {
    int m = blockIdx.x * 256 + threadIdx.x;
    if (m < M) out[m] = b3[0];
}

// ---------------------------------------------------------------------------
// Kernel 3: GEMM  C[M,N] = relu(A[M,K] * BT[N,K]^T + bias)
// m97 structure: 128x128 tile, BK=32, 4 waves 2x2, 16x16x32 bf16 MFMA,
// global_load_lds width 16. Inner loop is EXACTLY the round-2 config
// (84 VGPR, 664 TF).
// LESSONS (do not re-try):
//  - R3: LDS XOR-swizzle killed conflicts (2.5e7 -> 0) but +4 VGPR crossed
//    the 6-waves/EU boundary -> SLOWER. Conflicts are hidden; occupancy isn't.
//  - R4: __launch_bounds__(256,6) capped regs below the 64-reg accumulator
//    -> scratch spills (FETCH 412MB -> 2.7GB), 5x slower. Never force
//    min-waves on this kernel.
// NEW (R5): XCD-aware supertile mapping, scalar math only. 1D grid; within a
// supertile of SS=8 row-panels x NCOL col-blocks, consecutive blocks walk
// ROWS fastest, so XCD k (= blk%8) re-reads one A row-panel (0.39 MB,
// L2-resident) across all columns. A is fetched from HBM ~once.
// FUSE: head layer folded into epilogue (lane16 shuffle-reduce + atomicAdd).
// ---------------------------------------------------------------------------
template <int NCOL, bool FUSE>
__global__ __launch_bounds__(256) void gemm_bt_bias_relu(
    const unsigned short* __restrict__ A,   // [M,K] bf16 bits
    const unsigned short* __restrict__ BT,  // [N,K] bf16 bits
    const float* __restrict__ bias,         // [N]
    unsigned short* __restrict__ C,         // [M,N] bf16 bits (unused if FUSE)
    const float* __restrict__ W3,           // [N] head weights (FUSE only)
    float* __restrict__ outp,               // [M] (FUSE only)
    int M, int N, int K) {
    __shared__ __align__(16) unsigned short As[128 * 32];
    __shared__ __align__(16) unsigned short Bs[128 * 32];

    const int tid = threadIdx.x;
    const int lane = tid & 63;
    const int wave = tid >> 6;
    const int wm = (wave >> 1) * 64;
    const int wn = (wave & 1) * 64;
    const int lane16 = lane & 15;
    const int quad = lane >> 4;

    // ---- supertile block mapping (all scalar; SS=8, perSup is pow2) ----
    const int SS = 8;
    const int nRow = M >> 7;
    const int perSup = SS * NCOL;
    const int nFull = nRow / SS;
    const int fullBlocks = nFull * perSup;
    const int blk = blockIdx.x;
    int row_blk, col_blk;
    if (blk < fullBlocks) {
        const int sup = blk / perSup;   // pow2 -> shift
        const int w = blk % perSup;
        row_blk = sup * SS + (w & (SS - 1));
        col_blk = w >> 3;               // / SS
    } else {
        const int rem = blk - fullBlocks;
        const int rt = nRow - nFull * SS;   // tail rows (6)
        row_blk = nFull * SS + rem % rt;
        col_blk = rem / rt;
    }

    const long row0 = (long)row_blk * 128;
    const long col0 = (long)col_blk * 128;

    const unsigned short* Ab = A + row0 * K;
    const unsigned short* Bb = BT + col0 * K;

    const int sr = tid >> 2;         // staging row 0..63
    const int sc = (tid & 3) * 8;    // staging col (elements)

    f32x4 acc[4][4];
    #pragma unroll
    for (int i = 0; i < 4; ++i)
        #pragma unroll
        for (int j = 0; j < 4; ++j)
            acc[i][j] = (f32x4){0.f, 0.f, 0.f, 0.f};

    for (int kt = 0; kt < K; kt += 32) {
        GLDS16(Ab + (long)sr * K + kt + sc,        As + tid * 8);
        GLDS16(Ab + (long)(sr + 64) * K + kt + sc, As + (256 + tid) * 8);
        GLDS16(Bb + (long)sr * K + kt + sc,        Bs + tid * 8);
        GLDS16(Bb + (long)(sr + 64) * K + kt + sc, Bs + (256 + tid) * 8);
        __syncthreads();

        bf16x8 af[4], bfr[4];
        #pragma unroll
        for (int i = 0; i < 4; ++i)
            af[i] = *(const bf16x8*)(As + (wm + i * 16 + lane16) * 32 + quad * 8);
        #pragma unroll
        for (int j = 0; j < 4; ++j)
            bfr[j] = *(const bf16x8*)(Bs + (wn + j * 16 + lane16) * 32 + quad * 8);

        #pragma unroll
        for (int i = 0; i < 4; ++i)
            #pragma unroll
            for (int j = 0; j < 4; ++j)
                acc[i][j] = __builtin_amdgcn_mfma_f32_16x16x32_bf16(
                    af[i], bfr[j], acc[i][j], 0, 0, 0);

        __syncthreads();
    }

    // Epilogue: C/D layout col=lane&15, row=quad*4+reg  (m89/m91 verified)
    if (!FUSE) {
        #pragma unroll
        for (int i = 0; i < 4; ++i) {
            #pragma unroll
            for (int r = 0; r < 4; ++r) {
                const long row = row0 + wm + i * 16 + quad * 4 + r;
                #pragma unroll
                for (int j = 0; j < 4; ++j) {
                    const long col = col0 + wn + j * 16 + lane16;
                    float v = acc[i][j][r] + bias[col];
                    v = fmaxf(v, 0.f);
                    C[row * N + col] = f2bs(v);
                }
            }
        }
    } else {
        // head fusion: sum over this lane's 4 cols of relu(v)*W3
        float w3v[4], bv[4];
        #pragma unroll
        for (int j = 0; j < 4; ++j) {
            const long col = col0 + wn + j * 16 + lane16;
            w3v[j] = W3[col];
            bv[j] = bias[col];
        }
        #pragma unroll
        for (int i = 0; i < 4; ++i) {
            #pragma unroll
            for (int r = 0; r < 4; ++r) {
                float s = 0.f;
                #pragma unroll
                for (int j = 0; j < 4; ++j) {
                    float v = fmaxf(acc[i][j][r] + bv[j], 0.f);
                    s += v * w3v[j];
                }
                s += __shfl_xor(s, 1, 64);
                s += __shfl_xor(s, 2, 64);
                s += __shfl_xor(s, 4, 64);
                s += __shfl_xor(s, 8, 64);
                if (lane16 == 0) {
                    const long row = row0 + wm + i * 16 + quad * 4 + r;
                    atomicAdd(&outp[row], s);
                }
            }
        }
    }
}

// ---------------------------------------------------------------------------
// Launch
// ---------------------------------------------------------------------------
extern "C" void kernel_launch(void* const* d_in, const int* in_sizes, int n_in,
                              void* d_out, int out_size, void* d_ws,
                              size_t ws_size, hipStream_t stream) {
    const float* h  = (const float*)d_in[0];
    const float* W1 = (const float*)d_in[1];
    const float* b1 = (const float*)d_in[2];
    const float* W2 = (const float*)d_in[3];
    const float* b2 = (const float*)d_in[4];
    const float* W3 = (const float*)d_in[5];
    const float* b3 = (const float*)d_in[6];
    float* out = (float*)d_out;

    const int B = 128, T = 254, D = 768, H = 1024;
    const int M = B * T;        // 32512
    const int K1 = 2 * D;       // 1536
    const int N1 = 2 * H;       // 2048
    const int K2 = N1;          // 2048
    const int N2 = H;           // 1024
    const int nC = (T + TCHUNK - 1) / TCHUNK;  // 8

    char* ws = (char*)d_ws;
    size_t off = 0;
    auto alloc = [&](size_t bytes) {
        char* p = ws + off;
        off += (bytes + 255) & ~(size_t)255;
        return p;
    };
    unsigned short* X   = (unsigned short*)alloc((size_t)M * K1 * 2);  // 99.9 MB
    unsigned short* H1  = (unsigned short*)alloc((size_t)M * N1 * 2);  // 133.2 MB
    unsigned short* W1T = (unsigned short*)alloc((size_t)N1 * K1 * 2); // 6.3 MB
    unsigned short* W2T = (unsigned short*)alloc((size_t)N2 * K2 * 2); // 4.2 MB
    float* partial      = (float*)alloc((size_t)B * nC * D * 4);       // 3.1 MB

    dim3 tb(32, 8);
    transpose_cast<<<dim3(N1 / 32, K1 / 32), tb, 0, stream>>>(W1, W1T, K1, N1);
    transpose_cast<<<dim3(N2 / 32, K2 / 32), tb, 0, stream>>>(W2, W2T, K2, N2);

    feats_partial<<<dim3(B, nC, D / 256), 256, 0, stream>>>(
        h, partial, B, T, D, nC);
    feats_write<<<dim3(B, nC, D / 256), 256, 0, stream>>>(
        h, partial, X, B, T, D, nC);

    init_out<<<dim3((M + 255) / 256), 256, 0, stream>>>(out, b3, M);

    // 1D grid with device-side supertile mapping (see kernel comment)
    gemm_bt_bias_relu<16, false><<<dim3((M / 128) * (N1 / 128)), 256, 0, stream>>>(
        X, W1T, b1, H1, nullptr, nullptr, M, N1, K1);
    gemm_bt_bias_relu<8, true><<<dim3((M / 128) * (N2 / 128)), 256, 0, stream>>>(
        H1, W2T, b2, nullptr, W3, out, M, N2, K2);
}